// Round 4
// baseline (338.629 us; speedup 1.0000x reference)
//
#include <hip/hip_runtime.h>

#define N_ROWS   1048576
#define T_COLS   32
#define NBLK     512
#define BLOCK    512               // 8 waves: wv>>2 = matrix, wv&3 = sub
#define WAVES_PB 8
#define ROWS_PER_WAVE 512
#define CH       32                // 16-row chunks per wave
#define DEPTH    6                 // register-pipeline depth (chunks in flight)
#define NWS      2080              // 1024 Gt + 1024 Gp + 32 colsums
#define NREP     64                // replicated accumulation slots in ws

typedef _Float16 half8    __attribute__((ext_vector_type(8)));
typedef float    f32x4    __attribute__((ext_vector_type(4)));
typedef float    floatx16 __attribute__((ext_vector_type(16)));

// Per-wave LDS: double-buffered 16x32 f32 chunk (2 KB each).
#define CHUNK_FLOATS 512
#define WAVE_BYTES   (2 * CHUNK_FLOATS * 4)
#define LDS_BYTES    (WAVES_PB * WAVE_BYTES)   // 32 KiB; s_red (8320 B) overlays

// Gram via mfma_f32_32x32x16_f16 with the SAME fragment as A and B (A/B lane
// maps identical: dim=lane&31, k=(lane>>5)*8+elem; any within-lane k-perm
// cancels A vs B; C/D transposition harmless since G is symmetric).
__global__ __launch_bounds__(BLOCK, 4) void ts_gram(const float* __restrict__ y_pred,
                                                    const float* __restrict__ y_true,
                                                    float* __restrict__ ws) {
    __shared__ alignas(16) char smem[LDS_BYTES];

    const int tid  = threadIdx.x;
    const int wv   = tid >> 6;
    const int mtx  = wv >> 2;          // 0 = y_true (waves 0-3), 1 = y_pred (waves 4-7)
    const int sub  = wv & 3;
    const int lane = tid & 63;
    const int hi   = lane >> 5;        // k-half within chunk (MFMA frag)
    const int col  = lane & 31;        // MFMA frag column
    const int lr   = lane >> 3;        // load/stage: row within 8-row group
    const int lg   = lane & 7;         // load/stage: col group (4 cols)

    const float* src = (mtx == 0) ? y_true : y_pred;
    const size_t row0 = (size_t)blockIdx.x * (4 * ROWS_PER_WAVE) + (size_t)sub * ROWS_PER_WAVE;
    // lane's load: row = row0 + lr (+16 per chunk, +8 for q=1), cols lg*4..+3
    const f32x4* gp = (const f32x4*)(src + (row0 + (size_t)lr) * T_COLS) + lg;

    float* lds = (float*)(smem + wv * WAVE_BYTES);   // wave-private: no barriers in loop

    f32x4 pf[DEPTH][2];                // rotating prefetch regs, all static-indexed
    floatx16 acc = {};
    float cs[4] = {0.f, 0.f, 0.f, 0.f};

    // chunk c, part q lives at gp + (c*16 + q*8) * 8  (f32x4 units; row stride = 8)
#define LOADC(c, s) do {                                                     \
        pf[s][0] = __builtin_nontemporal_load(&gp[((c) * 16 + 0) * 8]);      \
        pf[s][1] = __builtin_nontemporal_load(&gp[((c) * 16 + 8) * 8]);      \
    } while (0)

    // stage chunk c (regs -> LDS buf c&1) + fold colsum from the f32 regs
#define STAGEC(c, s) do {                                                    \
        float* wp_ = lds + ((c) & 1) * CHUNK_FLOATS + lr * T_COLS + lg * 4;  \
        _Pragma("unroll")                                                    \
        for (int q_ = 0; q_ < 2; ++q_) {                                     \
            *(f32x4*)(wp_ + q_ * 8 * T_COLS) = pf[s][q_];                    \
            if (mtx == 0) {                                                  \
                cs[0] += pf[s][q_][0]; cs[1] += pf[s][q_][1];                \
                cs[2] += pf[s][q_][2]; cs[3] += pf[s][q_][3];                \
            }                                                                \
        }                                                                    \
    } while (0)

    // Prologue: fill the register pipeline (12 x 1KB dwordx4 loads in flight)
    #pragma unroll
    for (int c = 0; c < DEPTH; ++c) LOADC(c, c);
    STAGEC(0, 0);

    #pragma unroll
    for (int c = 0; c < CH; ++c) {
        // stage next chunk (compiler inserts the counted vmcnt for its regs)
        if (c + 1 < CH) STAGEC(c + 1, (c + 1) % DEPTH);
        // refill the slot just freed (chunk c's regs were staged last iter)
        if (c + DEPTH < CH) LOADC(c + DEPTH, c % DEPTH);

        // frag read chunk c: lds[(c&1)][hi*8+j][col] -> bank=col, 2 lanes/bank
        const float* rp = lds + (c & 1) * CHUNK_FLOATS + hi * 8 * T_COLS + col;
        float v[8];
        #pragma unroll
        for (int j = 0; j < 8; ++j) v[j] = rp[j * T_COLS];

        half8 h;
        #pragma unroll
        for (int j = 0; j < 8; ++j) h[j] = (_Float16)v[j];
        acc = __builtin_amdgcn_mfma_f32_32x32x16_f16(h, h, acc, 0, 0, 0);
    }
#undef LOADC
#undef STAGEC

    // ---- block reduction (s_red overlays staging LDS) ----
    __syncthreads();
    float* s_red = (float*)smem;
    for (int i = tid; i < NWS; i += BLOCK) s_red[i] = 0.0f;
    __syncthreads();
    // C/D layout (m74/m101, dtype-independent): col=lane&31,
    // row=(r&3)+8*(r>>2)+4*(lane>>5). 4-way collisions (sub 0..3).
    #pragma unroll
    for (int r = 0; r < 16; ++r) {
        int row = (r & 3) + 8 * (r >> 2) + 4 * hi;
        atomicAdd(&s_red[mtx * 1024 + row * 32 + col], acc[r]);
    }
    if (mtx == 0) {
        // lanes sharing lg hold partials for cols lg*4..+3; reduce over lr bits
        #pragma unroll
        for (int k = 0; k < 4; ++k) {
            cs[k] += __shfl_xor(cs[k], 8);
            cs[k] += __shfl_xor(cs[k], 16);
            cs[k] += __shfl_xor(cs[k], 32);
        }
        if (lr == 0) {
            #pragma unroll
            for (int k = 0; k < 4; ++k) atomicAdd(&s_red[2048 + lg * 4 + k], cs[k]);
        }
    }
    __syncthreads();
    // replica slot spreads global-atomic contention (8 blocks per address)
    float* wsr = ws + (size_t)(blockIdx.x & (NREP - 1)) * NWS;
    for (int i = tid; i < NWS; i += BLOCK) atomicAdd(&wsr[i], s_red[i]);
}

__global__ __launch_bounds__(1024) void ts_final(const float* __restrict__ w,
                                                 float* __restrict__ out) {
    __shared__ float s_w[NWS];
    __shared__ float s_S[32], s_nx[32], s_pn[32];
    __shared__ float s_red[16];
    const int tid = threadIdx.x;
    const float invN = 1.0f / (float)N_ROWS;

    // sum the NREP replica slots (coalesced)
    for (int i = tid; i < NWS; i += 1024) {
        float t = 0.0f;
        #pragma unroll 4
        for (int r = 0; r < NREP; ++r) t += w[(size_t)r * NWS + i];
        s_w[i] = t;
    }
    __syncthreads();

    if (tid < 32) {
        float S = s_w[2048 + tid];
        s_S[tid] = S;
        float d = s_w[tid * 32 + tid] - S * S * invN;   // centered diag
        s_nx[tid] = sqrtf(d);
        s_pn[tid] = sqrtf(s_w[1024 + tid * 33]);
    }
    __syncthreads();

    const int j = tid >> 5, k = tid & 31;
    float contrib = 0.0f;
    if (j >= 1 && k > j && j < 32) {
        float gc  = s_w[j * 32 + k] - s_S[j] * s_S[k] * invN;
        float pcc = gc / (s_nx[j] * s_nx[k]);
        float cs  = s_w[1024 + j * 32 + k] / fmaxf(s_pn[j] * s_pn[k], 1e-8f);
        if (pcc >= 0.0f) contrib = 1.0f - cs;
    }
    #pragma unroll
    for (int off = 32; off > 0; off >>= 1) contrib += __shfl_down(contrib, off);
    if ((tid & 63) == 0) s_red[tid >> 6] = contrib;
    __syncthreads();
    if (tid == 0) {
        float tot = 0.0f;
        #pragma unroll
        for (int i = 0; i < 16; ++i) tot += s_red[i];
        out[0] = tot * (1.0f / 465.0f);   // c = (T-1)(T-2)/2
    }
}

extern "C" void kernel_launch(void* const* d_in, const int* in_sizes, int n_in,
                              void* d_out, int out_size, void* d_ws, size_t ws_size,
                              hipStream_t stream) {
    const float* y_pred = (const float*)d_in[0];
    const float* y_true = (const float*)d_in[1];
    float* out = (float*)d_out;
    float* ws  = (float*)d_ws;

    hipMemsetAsync(ws, 0, (size_t)NREP * NWS * sizeof(float), stream);
    ts_gram<<<NBLK, BLOCK, 0, stream>>>(y_pred, y_true, ws);
    ts_final<<<1, 1024, 0, stream>>>(ws, out);
}